// Round 16
// baseline (195.726 us; speedup 1.0000x reference)
//
#include <hip/hip_runtime.h>
#include <hip/hip_bf16.h>

typedef __attribute__((ext_vector_type(8))) short bf16x8;
typedef __attribute__((ext_vector_type(4))) float f32x4;
typedef __attribute__((ext_vector_type(8))) unsigned short u16x8;
typedef __attribute__((ext_vector_type(4))) unsigned short u16x4;

static __device__ __forceinline__ unsigned short f2bf(float f) {
  __hip_bfloat16 h = __float2bfloat16(f);
  union { __hip_bfloat16 h; unsigned short u; } cv; cv.h = h; return cv.u;
}
static __device__ __forceinline__ float bf2f(unsigned short u) {
  union { unsigned int u; float f; } cv; cv.u = ((unsigned int)u) << 16; return cv.f;
}

static __device__ __forceinline__ void gload16(const unsigned short* g, unsigned short* l) {
  __builtin_amdgcn_global_load_lds((const __attribute__((address_space(1))) void*)g,
                                   (__attribute__((address_space(3))) void*)l, 16, 0, 0);
}

#define BK 64

// D[M][N] = A[M][K] x BT[N][K]^T, bf16 out.  256x256 tile, BK=64, 16 waves
// (1024 thr), per-wave 64x64 (same register economy as R10: acc=64 VGPR).
// R16 theory: per-CU staging throughput is capped ~16B/cyc INDEPENDENT of
// schedule/occupancy (R4/R10/R13/R7/R14 all fit); the only lever left is
// staged-bytes-per-output: 256x256 stages 8B/out vs 128x128's 16B/out.
// K-loop schedule and swizzle pair identical to R10/R15 (verified).
// Single 64KB LDS buffer, 1 block/CU (16 waves = R10's per-CU wave count).
// XCD-swizzled block id (grids % 8 == 0).
__global__ __launch_bounds__(1024, 4) void gemm_bt(
    const unsigned short* __restrict__ A, const unsigned short* __restrict__ Bm,
    long sA, long sB, int lda, int ldb, int K,
    const float* __restrict__ bias, int bias_mode, float post_scale,
    unsigned short* __restrict__ D, long sD, int ldd)
{
  __shared__ unsigned short lA[256 * BK];   // 32KB
  __shared__ unsigned short lB[256 * BK];   // 32KB
  const int gx = gridDim.x, gy = gridDim.y;
  const int nwg = gx * gy * gridDim.z;
  int orig = blockIdx.x + gx * (blockIdx.y + gy * blockIdx.z);
  int id = (orig & 7) * (nwg >> 3) + (orig >> 3);   // bijective: nwg % 8 == 0
  const int bxi = id % gx;
  int rem = id / gx;
  const int byi = rem % gy;
  const int bz = rem / gy;

  const int tid = threadIdx.x, lane = tid & 63, wid = tid >> 6;
  const int l15 = lane & 15, lhi = lane >> 4;
  const int wr = wid >> 2, wc = wid & 3;            // 4x4 wave grid, 64x64 each
  const long bm = (long)byi * 256, bn = (long)bxi * 256;
  const unsigned short* Ab = A + (size_t)bz * sA + (size_t)bm * lda;
  const unsigned short* Bb = Bm + (size_t)bz * sB + (size_t)bn * ldb;
  const int NT = K >> 6;                            // K multiple of 64

  f32x4 acc[4][4];
  #pragma unroll
  for (int i = 0; i < 4; ++i)
    #pragma unroll
    for (int j = 0; j < 4; ++j) acc[i][j] = (f32x4){0.f, 0.f, 0.f, 0.f};

  // Stage 256x64 tiles: 2048 16B-chunks per operand, 2/thread.
  // LDS linear (wave-uniform base + lane*16B); global source pre-swizzled
  // kb = sl ^ (row&7), matching the fragment-read XOR (verified, 0 confl).
  auto stage = [&](int k0) {
    #pragma unroll
    for (int j = 0; j < 2; ++j) {
      int bi = j * 1024 + tid;
      int row = bi >> 3, sl = bi & 7;
      int kb = sl ^ (row & 7);
      gload16(Ab + (size_t)row * lda + k0 + kb * 8, &lA[(j * 1024 + wid * 64) * 8]);
    }
    #pragma unroll
    for (int j = 0; j < 2; ++j) {
      int bi = j * 1024 + tid;
      int row = bi >> 3, sl = bi & 7;
      int kb = sl ^ (row & 7);
      gload16(Bb + (size_t)row * ldb + k0 + kb * 8, &lB[(j * 1024 + wid * 64) * 8]);
    }
  };

  for (int t = 0; t < NT; ++t) {
    stage(t * BK);
    __syncthreads();                    // vmcnt(0)+barrier: tile resident
    #pragma unroll
    for (int s = 0; s < 2; ++s) {
      bf16x8 af[4], bfr[4];
      #pragma unroll
      for (int mi = 0; mi < 4; ++mi) {
        int row = wr * 64 + mi * 16 + l15;
        int sl = (s * 4 + lhi) ^ (row & 7);
        af[mi] = *(const bf16x8*)&lA[row * BK + sl * 8];
      }
      #pragma unroll
      for (int ni = 0; ni < 4; ++ni) {
        int row = wc * 64 + ni * 16 + l15;
        int sl = (s * 4 + lhi) ^ (row & 7);
        bfr[ni] = *(const bf16x8*)&lB[row * BK + sl * 8];
      }
      #pragma unroll
      for (int mi = 0; mi < 4; ++mi)
        #pragma unroll
        for (int ni = 0; ni < 4; ++ni)
          acc[mi][ni] = __builtin_amdgcn_mfma_f32_16x16x32_bf16(af[mi], bfr[ni], acc[mi][ni], 0, 0, 0);
    }
    __syncthreads();                    // WAR: reads done before next stage
  }

  #pragma unroll
  for (int mi = 0; mi < 4; ++mi) {
    #pragma unroll
    for (int ni = 0; ni < 4; ++ni) {
      #pragma unroll
      for (int r = 0; r < 4; ++r) {
        long row = bm + wr * 64 + mi * 16 + lhi * 4 + r;
        long col = bn + wc * 64 + ni * 16 + l15;
        float v = acc[mi][ni][r];
        if (bias_mode == 1) v += bias[row];
        else if (bias_mode == 2) v += bias[col];
        v *= post_scale;
        D[(size_t)bz * sD + (size_t)row * ldd + col] = f2bf(v);
      }
    }
  }
}

// Single-pass GroupNorm; writes h transposed: ht[b][n][c] bf16.
__global__ __launch_bounds__(256) void groupnorm_to_ht(
    const float* __restrict__ x, const float* __restrict__ gamma,
    const float* __restrict__ beta, unsigned short* __restrict__ ht)
{
  const int b = blockIdx.x >> 5;
  const int g = blockIdx.x & 31;
  const int tid = threadIdx.x, lane = tid & 63, wid = tid >> 6;
  const float4* xg4 = (const float4*)(x + ((size_t)b * 512 + g * 16) * 1024);
  float4 v[16];
  float s = 0.f, ss = 0.f;
  #pragma unroll
  for (int j = 0; j < 16; ++j) {
    v[j] = xg4[j * 256 + tid];
    s += v[j].x + v[j].y + v[j].z + v[j].w;
    ss += v[j].x * v[j].x + v[j].y * v[j].y + v[j].z * v[j].z + v[j].w * v[j].w;
  }
  #pragma unroll
  for (int o = 32; o; o >>= 1) { s += __shfl_xor(s, o); ss += __shfl_xor(ss, o); }
  __shared__ float red[8];
  if (lane == 0) { red[wid] = s; red[4 + wid] = ss; }
  __syncthreads();
  s = red[0] + red[1] + red[2] + red[3];
  ss = red[4] + red[5] + red[6] + red[7];
  const float mu = s * (1.f / 16384.f);
  const float var = ss * (1.f / 16384.f) - mu * mu;
  const float rsig = rsqrtf(var + 1e-5f);
  __shared__ unsigned short tile[16][1024];
  #pragma unroll
  for (int j = 0; j < 16; ++j) {
    int e = (j * 256 + tid) * 4;
    int ci = e >> 10, n = e & 1023;
    float ga = gamma[g * 16 + ci] * rsig, be = beta[g * 16 + ci];
    u16x4 o = { f2bf((v[j].x - mu) * ga + be), f2bf((v[j].y - mu) * ga + be),
                f2bf((v[j].z - mu) * ga + be), f2bf((v[j].w - mu) * ga + be) };
    *(u16x4*)&tile[ci][n] = o;
  }
  __syncthreads();
  unsigned short* hb = ht + (size_t)b * 1024 * 512 + g * 16;
  for (int rep = 0; rep < 4; ++rep) {
    int n = rep * 256 + tid;
    u16x8 lo, hi;
    #pragma unroll
    for (int ci = 0; ci < 8; ++ci) lo[ci] = tile[ci][n];
    #pragma unroll
    for (int ci = 0; ci < 8; ++ci) hi[ci] = tile[8 + ci][n];
    *(u16x8*)&hb[(size_t)n * 512] = lo;
    *(u16x8*)&hb[(size_t)n * 512 + 8] = hi;
  }
}

// Row softmax in place over 1024 bf16 logits; one wave per row.
__global__ __launch_bounds__(256) void softmax_rows(unsigned short* __restrict__ attn)
{
  int row = blockIdx.x * 4 + (threadIdx.x >> 6);
  int lane = threadIdx.x & 63;
  unsigned short* p = attn + (size_t)row * 1024;
  u16x8 c0 = *(const u16x8*)&p[lane * 8];
  u16x8 c1 = *(const u16x8*)&p[512 + lane * 8];
  float f[16];
  #pragma unroll
  for (int j = 0; j < 8; ++j) { f[j] = bf2f(c0[j]); f[8 + j] = bf2f(c1[j]); }
  float m = f[0];
  #pragma unroll
  for (int j = 1; j < 16; ++j) m = fmaxf(m, f[j]);
  #pragma unroll
  for (int o = 32; o; o >>= 1) m = fmaxf(m, __shfl_xor(m, o));
  float sum = 0.f;
  #pragma unroll
  for (int j = 0; j < 16; ++j) { f[j] = __expf(f[j] - m); sum += f[j]; }
  #pragma unroll
  for (int o = 32; o; o >>= 1) sum += __shfl_xor(sum, o);
  float inv = 1.0f / sum;
  #pragma unroll
  for (int j = 0; j < 8; ++j) { c0[j] = f2bf(f[j] * inv); c1[j] = f2bf(f[8 + j] * inv); }
  *(u16x8*)&p[lane * 8] = c0;
  *(u16x8*)&p[512 + lane * 8] = c1;
}

// out[b][c][n] = x[b][c][n] + po[c][b*1024+n]   (fp32 residual, vectorized)
// 8,388,608 elems / 8 per thread = 4096 blocks of 256.
__global__ __launch_bounds__(256) void residual_add(
    const float* __restrict__ x, const unsigned short* __restrict__ po,
    float* __restrict__ out)
{
  int t = blockIdx.x * 256 + threadIdx.x;
  int idx = t * 8;
  int b = idx >> 19, c = (idx >> 10) & 511, n = idx & 1023;
  u16x8 g = *(const u16x8*)&po[(size_t)c * 16384 + b * 1024 + n];
  float4 x0 = *(const float4*)&x[idx];
  float4 x1 = *(const float4*)&x[idx + 4];
  float4 o0 = { x0.x + bf2f(g[0]), x0.y + bf2f(g[1]), x0.z + bf2f(g[2]), x0.w + bf2f(g[3]) };
  float4 o1 = { x1.x + bf2f(g[4]), x1.y + bf2f(g[5]), x1.z + bf2f(g[6]), x1.w + bf2f(g[7]) };
  *(float4*)&out[idx] = o0;
  *(float4*)&out[idx + 4] = o1;
}

__global__ __launch_bounds__(256) void convert_weights(
    const float* __restrict__ wq, const float* __restrict__ wk,
    const float* __restrict__ wv, const float* __restrict__ wp,
    const float* __restrict__ bq, const float* __restrict__ bk,
    unsigned short* __restrict__ out, float* __restrict__ bqk)
{
  if (blockIdx.x == 1024) {          // build concatenated q||k bias
    int i = threadIdx.x * 4;
    if (i < 512) *(float4*)&bqk[i] = *(const float4*)&bq[i];
    else         *(float4*)&bqk[i] = *(const float4*)&bk[i - 512];
    return;
  }
  int t = blockIdx.x * 256 + threadIdx.x;
  int m = t >> 16;
  int off = (t & 65535) * 4;
  const float* src = m == 0 ? wq : m == 1 ? wk : m == 2 ? wv : wp;
  float4 v = *(const float4*)&src[off];
  u16x4 o = { f2bf(v.x), f2bf(v.y), f2bf(v.z), f2bf(v.w) };
  *(u16x4*)&out[(size_t)m * 262144 + off] = o;
}

extern "C" void kernel_launch(void* const* d_in, const int* in_sizes, int n_in,
                              void* d_out, int out_size, void* d_ws, size_t ws_size,
                              hipStream_t stream)
{
  const float* x     = (const float*)d_in[0];
  const float* gamma = (const float*)d_in[1];
  const float* beta  = (const float*)d_in[2];
  const float* wq    = (const float*)d_in[3];
  const float* bq    = (const float*)d_in[4];
  const float* wk    = (const float*)d_in[5];
  const float* bk    = (const float*)d_in[6];
  const float* wv    = (const float*)d_in[7];
  const float* bv    = (const float*)d_in[8];
  const float* wp    = (const float*)d_in[9];
  const float* bp    = (const float*)d_in[10];

  unsigned short* ws   = (unsigned short*)d_ws;
  unsigned short* w_bf = ws;                               // [4][512][512]
  unsigned short* ht   = w_bf + 1048576;                   // [B*N][C]
  unsigned short* qk   = ht + 8388608;                     // [B*N][2C]  (q||k)
  unsigned short* vv2  = qk + 16777216;                    // [C][B*N]
  unsigned short* attn = vv2 + 8388608;                    // [B][N][N]; reused as po [C][B*N]
  unsigned short* ot   = attn + 16777216;                  // [B*N][C]
  float*          bqk  = (float*)(ot + 8388608);           // [1024]
  unsigned short* po   = attn;                             // reuse after PV

  const float scale = 0.044194173824159216f;               // 512^-0.5

  convert_weights<<<dim3(1025), dim3(256), 0, stream>>>(wq, wk, wv, wp, bq, bk, w_bf, bqk);
  groupnorm_to_ht<<<dim3(512), dim3(256), 0, stream>>>(x, gamma, beta, ht);

  // qk[bn][0..1024) = ht x [wq;wk]^T + (bq||bk)       M=16384 N=1024 K=512
  gemm_bt<<<dim3(4, 64, 1), dim3(1024), 0, stream>>>(
      ht, w_bf, 0L, 0L, 512, 512, 512,
      bqk, 2, 1.0f, qk, 0L, 1024);
  // vv2[c][bn] = wv x h + bv                           M=512 N=16384 K=512
  gemm_bt<<<dim3(64, 2, 1), dim3(1024), 0, stream>>>(
      w_bf + 2 * 262144, ht, 0L, 0L, 512, 512, 512,
      bv, 1, 1.0f, vv2, 0L, 16384);
  // attn[b][n][m] = scale * (q_n . k_m)                M=1024 N=1024 K=512, z=16
  gemm_bt<<<dim3(4, 4, 16), dim3(1024), 0, stream>>>(
      qk, qk + 512, 1048576L, 1048576L, 1024, 1024, 512,
      (const float*)nullptr, 0, scale, attn, 1048576L, 1024);
  softmax_rows<<<dim3(4096), dim3(256), 0, stream>>>(attn);
  // ot[b][n][c] = attn x v^T                           M=1024 N=512 K=1024, z=16
  gemm_bt<<<dim3(2, 4, 16), dim3(1024), 0, stream>>>(
      attn, vv2, 1048576L, 1024L, 1024, 16384, 1024,
      (const float*)nullptr, 0, 1.0f, ot, 524288L, 512);
  // po[c][bn] = wp x o + bp                            M=512 N=16384 K=512
  gemm_bt<<<dim3(64, 2, 1), dim3(1024), 0, stream>>>(
      w_bf + 3 * 262144, ot, 0L, 0L, 512, 512, 512,
      bp, 1, 1.0f, po, 0L, 16384);
  // out = x + po  (fp32)
  residual_add<<<dim3(4096), dim3(256), 0, stream>>>(x, po, (float*)d_out);
}

// Round 17
// 175.435 us; speedup vs baseline: 1.1157x; 1.1157x over previous
//
#include <hip/hip_runtime.h>
#include <hip/hip_bf16.h>

typedef __attribute__((ext_vector_type(8))) short bf16x8;
typedef __attribute__((ext_vector_type(4))) float f32x4;
typedef __attribute__((ext_vector_type(8))) unsigned short u16x8;
typedef __attribute__((ext_vector_type(4))) unsigned short u16x4;

static __device__ __forceinline__ unsigned short f2bf(float f) {
  __hip_bfloat16 h = __float2bfloat16(f);
  union { __hip_bfloat16 h; unsigned short u; } cv; cv.h = h; return cv.u;
}
static __device__ __forceinline__ float bf2f(unsigned short u) {
  union { unsigned int u; float f; } cv; cv.u = ((unsigned int)u) << 16; return cv.f;
}

static __device__ __forceinline__ void gload16(const unsigned short* g, unsigned short* l) {
  __builtin_amdgcn_global_load_lds((const __attribute__((address_space(1))) void*)g,
                                   (__attribute__((address_space(3))) void*)l, 16, 0, 0);
}

#define BK 64

// D[M][N] = A[M][K] x BT[N][K]^T, bf16 out.  256x256 tile, BK=64, 16 waves
// (1024 thr, 4x4 wave grid, 64x64/wave — R16's verified mappings), but with
// the T3-minimum schedule R16 lacked: DOUBLE-buffered 128KB LDS, stage(next)
// issued BEFORE compute(cur), ONE __syncthreads per K-step (its vmcnt(0)
// drain lands after the MFMA phase has covered most of the load latency).
// m230/m248 measured this 256^2+2-phase structure at 655-682 TF refcheck'd.
// XCD-swizzled block id (grids % 8 == 0).
__global__ __launch_bounds__(1024, 4) void gemm_bt(
    const unsigned short* __restrict__ A, const unsigned short* __restrict__ Bm,
    long sA, long sB, int lda, int ldb, int K,
    const float* __restrict__ bias, int bias_mode, float post_scale,
    unsigned short* __restrict__ D, long sD, int ldd)
{
  extern __shared__ unsigned short lds[];   // [2][ A 16384 | B 16384 ] ushorts = 128KB
  const int gx = gridDim.x, gy = gridDim.y;
  const int nwg = gx * gy * gridDim.z;
  int orig = blockIdx.x + gx * (blockIdx.y + gy * blockIdx.z);
  int id = (orig & 7) * (nwg >> 3) + (orig >> 3);   // bijective: nwg % 8 == 0
  const int bxi = id % gx;
  int rem = id / gx;
  const int byi = rem % gy;
  const int bz = rem / gy;

  const int tid = threadIdx.x, lane = tid & 63, wid = tid >> 6;
  const int l15 = lane & 15, lhi = lane >> 4;
  const int wr = wid >> 2, wc = wid & 3;            // 4x4 wave grid, 64x64 each
  const long bm = (long)byi * 256, bn = (long)bxi * 256;
  const unsigned short* Ab = A + (size_t)bz * sA + (size_t)bm * lda;
  const unsigned short* Bb = Bm + (size_t)bz * sB + (size_t)bn * ldb;
  const int NT = K >> 6;                            // K multiple of 64

  f32x4 acc[4][4];
  #pragma unroll
  for (int i = 0; i < 4; ++i)
    #pragma unroll
    for (int j = 0; j < 4; ++j) acc[i][j] = (f32x4){0.f, 0.f, 0.f, 0.f};

  // Stage 256x64 tiles into dbuf slot: 2048 16B-chunks per operand, 2/thread.
  // LDS linear (wave-uniform base + lane*16B); global source pre-swizzled
  // kb = sl ^ (row&7), matching the fragment-read XOR (verified R16, 0 confl).
  auto stage = [&](int buf, int k0) {
    unsigned short* la = lds + buf * 32768;
    unsigned short* lb = la + 16384;
    #pragma unroll
    for (int j = 0; j < 2; ++j) {
      int bi = j * 1024 + tid;
      int row = bi >> 3, sl = bi & 7;
      int kb = sl ^ (row & 7);
      gload16(Ab + (size_t)row * lda + k0 + kb * 8, &la[(j * 1024 + wid * 64) * 8]);
    }
    #pragma unroll
    for (int j = 0; j < 2; ++j) {
      int bi = j * 1024 + tid;
      int row = bi >> 3, sl = bi & 7;
      int kb = sl ^ (row & 7);
      gload16(Bb + (size_t)row * ldb + k0 + kb * 8, &lb[(j * 1024 + wid * 64) * 8]);
    }
  };

  stage(0, 0);
  __syncthreads();                        // tile 0 resident
  int buf = 0;
  for (int t = 0; t < NT; ++t) {
    if (t + 1 < NT) stage(buf ^ 1, (t + 1) * BK);   // in flight across compute
    const unsigned short* la = lds + buf * 32768;
    const unsigned short* lb = la + 16384;
    #pragma unroll
    for (int s = 0; s < 2; ++s) {
      bf16x8 af[4], bfr[4];
      #pragma unroll
      for (int mi = 0; mi < 4; ++mi) {
        int row = wr * 64 + mi * 16 + l15;
        int sl = (s * 4 + lhi) ^ (row & 7);
        af[mi] = *(const bf16x8*)&la[row * BK + sl * 8];
      }
      #pragma unroll
      for (int ni = 0; ni < 4; ++ni) {
        int row = wc * 64 + ni * 16 + l15;
        int sl = (s * 4 + lhi) ^ (row & 7);
        bfr[ni] = *(const bf16x8*)&lb[row * BK + sl * 8];
      }
      #pragma unroll
      for (int mi = 0; mi < 4; ++mi)
        #pragma unroll
        for (int ni = 0; ni < 4; ++ni)
          acc[mi][ni] = __builtin_amdgcn_mfma_f32_16x16x32_bf16(af[mi], bfr[ni], acc[mi][ni], 0, 0, 0);
    }
    __syncthreads();    // single barrier/step: drains stage(buf^1), guards WAR on buf
    buf ^= 1;
  }

  #pragma unroll
  for (int mi = 0; mi < 4; ++mi) {
    #pragma unroll
    for (int ni = 0; ni < 4; ++ni) {
      #pragma unroll
      for (int r = 0; r < 4; ++r) {
        long row = bm + wr * 64 + mi * 16 + lhi * 4 + r;
        long col = bn + wc * 64 + ni * 16 + l15;
        float v = acc[mi][ni][r];
        if (bias_mode == 1) v += bias[row];
        else if (bias_mode == 2) v += bias[col];
        v *= post_scale;
        D[(size_t)bz * sD + (size_t)row * ldd + col] = f2bf(v);
      }
    }
  }
}

// Single-pass GroupNorm; writes h transposed: ht[b][n][c] bf16.
__global__ __launch_bounds__(256) void groupnorm_to_ht(
    const float* __restrict__ x, const float* __restrict__ gamma,
    const float* __restrict__ beta, unsigned short* __restrict__ ht)
{
  const int b = blockIdx.x >> 5;
  const int g = blockIdx.x & 31;
  const int tid = threadIdx.x, lane = tid & 63, wid = tid >> 6;
  const float4* xg4 = (const float4*)(x + ((size_t)b * 512 + g * 16) * 1024);
  float4 v[16];
  float s = 0.f, ss = 0.f;
  #pragma unroll
  for (int j = 0; j < 16; ++j) {
    v[j] = xg4[j * 256 + tid];
    s += v[j].x + v[j].y + v[j].z + v[j].w;
    ss += v[j].x * v[j].x + v[j].y * v[j].y + v[j].z * v[j].z + v[j].w * v[j].w;
  }
  #pragma unroll
  for (int o = 32; o; o >>= 1) { s += __shfl_xor(s, o); ss += __shfl_xor(ss, o); }
  __shared__ float red[8];
  if (lane == 0) { red[wid] = s; red[4 + wid] = ss; }
  __syncthreads();
  s = red[0] + red[1] + red[2] + red[3];
  ss = red[4] + red[5] + red[6] + red[7];
  const float mu = s * (1.f / 16384.f);
  const float var = ss * (1.f / 16384.f) - mu * mu;
  const float rsig = rsqrtf(var + 1e-5f);
  __shared__ unsigned short tile[16][1024];
  #pragma unroll
  for (int j = 0; j < 16; ++j) {
    int e = (j * 256 + tid) * 4;
    int ci = e >> 10, n = e & 1023;
    float ga = gamma[g * 16 + ci] * rsig, be = beta[g * 16 + ci];
    u16x4 o = { f2bf((v[j].x - mu) * ga + be), f2bf((v[j].y - mu) * ga + be),
                f2bf((v[j].z - mu) * ga + be), f2bf((v[j].w - mu) * ga + be) };
    *(u16x4*)&tile[ci][n] = o;
  }
  __syncthreads();
  unsigned short* hb = ht + (size_t)b * 1024 * 512 + g * 16;
  for (int rep = 0; rep < 4; ++rep) {
    int n = rep * 256 + tid;
    u16x8 lo, hi;
    #pragma unroll
    for (int ci = 0; ci < 8; ++ci) lo[ci] = tile[ci][n];
    #pragma unroll
    for (int ci = 0; ci < 8; ++ci) hi[ci] = tile[8 + ci][n];
    *(u16x8*)&hb[(size_t)n * 512] = lo;
    *(u16x8*)&hb[(size_t)n * 512 + 8] = hi;
  }
}

// Row softmax in place over 1024 bf16 logits; one wave per row.
__global__ __launch_bounds__(256) void softmax_rows(unsigned short* __restrict__ attn)
{
  int row = blockIdx.x * 4 + (threadIdx.x >> 6);
  int lane = threadIdx.x & 63;
  unsigned short* p = attn + (size_t)row * 1024;
  u16x8 c0 = *(const u16x8*)&p[lane * 8];
  u16x8 c1 = *(const u16x8*)&p[512 + lane * 8];
  float f[16];
  #pragma unroll
  for (int j = 0; j < 8; ++j) { f[j] = bf2f(c0[j]); f[8 + j] = bf2f(c1[j]); }
  float m = f[0];
  #pragma unroll
  for (int j = 1; j < 16; ++j) m = fmaxf(m, f[j]);
  #pragma unroll
  for (int o = 32; o; o >>= 1) m = fmaxf(m, __shfl_xor(m, o));
  float sum = 0.f;
  #pragma unroll
  for (int j = 0; j < 16; ++j) { f[j] = __expf(f[j] - m); sum += f[j]; }
  #pragma unroll
  for (int o = 32; o; o >>= 1) sum += __shfl_xor(sum, o);
  float inv = 1.0f / sum;
  #pragma unroll
  for (int j = 0; j < 8; ++j) { c0[j] = f2bf(f[j] * inv); c1[j] = f2bf(f[8 + j] * inv); }
  *(u16x8*)&p[lane * 8] = c0;
  *(u16x8*)&p[512 + lane * 8] = c1;
}

// out[b][c][n] = x[b][c][n] + po[c][b*1024+n]   (fp32 residual, vectorized)
__global__ __launch_bounds__(256) void residual_add(
    const float* __restrict__ x, const unsigned short* __restrict__ po,
    float* __restrict__ out)
{
  int t = blockIdx.x * 256 + threadIdx.x;
  int idx = t * 8;
  int b = idx >> 19, c = (idx >> 10) & 511, n = idx & 1023;
  u16x8 g = *(const u16x8*)&po[(size_t)c * 16384 + b * 1024 + n];
  float4 x0 = *(const float4*)&x[idx];
  float4 x1 = *(const float4*)&x[idx + 4];
  float4 o0 = { x0.x + bf2f(g[0]), x0.y + bf2f(g[1]), x0.z + bf2f(g[2]), x0.w + bf2f(g[3]) };
  float4 o1 = { x1.x + bf2f(g[4]), x1.y + bf2f(g[5]), x1.z + bf2f(g[6]), x1.w + bf2f(g[7]) };
  *(float4*)&out[idx] = o0;
  *(float4*)&out[idx + 4] = o1;
}

__global__ __launch_bounds__(256) void convert_weights(
    const float* __restrict__ wq, const float* __restrict__ wk,
    const float* __restrict__ wv, const float* __restrict__ wp,
    const float* __restrict__ bq, const float* __restrict__ bk,
    unsigned short* __restrict__ out, float* __restrict__ bqk)
{
  if (blockIdx.x == 1024) {          // build concatenated q||k bias
    int i = threadIdx.x * 4;
    if (i < 512) *(float4*)&bqk[i] = *(const float4*)&bq[i];
    else         *(float4*)&bqk[i] = *(const float4*)&bk[i - 512];
    return;
  }
  int t = blockIdx.x * 256 + threadIdx.x;
  int m = t >> 16;
  int off = (t & 65535) * 4;
  const float* src = m == 0 ? wq : m == 1 ? wk : m == 2 ? wv : wp;
  float4 v = *(const float4*)&src[off];
  u16x4 o = { f2bf(v.x), f2bf(v.y), f2bf(v.z), f2bf(v.w) };
  *(u16x4*)&out[(size_t)m * 262144 + off] = o;
}

extern "C" void kernel_launch(void* const* d_in, const int* in_sizes, int n_in,
                              void* d_out, int out_size, void* d_ws, size_t ws_size,
                              hipStream_t stream)
{
  const float* x     = (const float*)d_in[0];
  const float* gamma = (const float*)d_in[1];
  const float* beta  = (const float*)d_in[2];
  const float* wq    = (const float*)d_in[3];
  const float* bq    = (const float*)d_in[4];
  const float* wk    = (const float*)d_in[5];
  const float* bk    = (const float*)d_in[6];
  const float* wv    = (const float*)d_in[7];
  const float* bv    = (const float*)d_in[8];
  const float* wp    = (const float*)d_in[9];
  const float* bp    = (const float*)d_in[10];

  unsigned short* ws   = (unsigned short*)d_ws;
  unsigned short* w_bf = ws;                               // [4][512][512]
  unsigned short* ht   = w_bf + 1048576;                   // [B*N][C]
  unsigned short* qk   = ht + 8388608;                     // [B*N][2C]  (q||k)
  unsigned short* vv2  = qk + 16777216;                    // [C][B*N]
  unsigned short* attn = vv2 + 8388608;                    // [B][N][N]; reused as po [C][B*N]
  unsigned short* ot   = attn + 16777216;                  // [B*N][C]
  float*          bqk  = (float*)(ot + 8388608);           // [1024]
  unsigned short* po   = attn;                             // reuse after PV

  const float scale = 0.044194173824159216f;               // 512^-0.5
  const int SMEM = 131072;
  hipFuncSetAttribute(reinterpret_cast<const void*>(&gemm_bt),
                      hipFuncAttributeMaxDynamicSharedMemorySize, SMEM);

  convert_weights<<<dim3(1025), dim3(256), 0, stream>>>(wq, wk, wv, wp, bq, bk, w_bf, bqk);
  groupnorm_to_ht<<<dim3(512), dim3(256), 0, stream>>>(x, gamma, beta, ht);

  // qk[bn][0..1024) = ht x [wq;wk]^T + (bq||bk)       M=16384 N=1024 K=512
  gemm_bt<<<dim3(4, 64, 1), dim3(1024), SMEM, stream>>>(
      ht, w_bf, 0L, 0L, 512, 512, 512,
      bqk, 2, 1.0f, qk, 0L, 1024);
  // vv2[c][bn] = wv x h + bv                           M=512 N=16384 K=512
  gemm_bt<<<dim3(64, 2, 1), dim3(1024), SMEM, stream>>>(
      w_bf + 2 * 262144, ht, 0L, 0L, 512, 512, 512,
      bv, 1, 1.0f, vv2, 0L, 16384);
  // attn[b][n][m] = scale * (q_n . k_m)                M=1024 N=1024 K=512, z=16
  gemm_bt<<<dim3(4, 4, 16), dim3(1024), SMEM, stream>>>(
      qk, qk + 512, 1048576L, 1048576L, 1024, 1024, 512,
      (const float*)nullptr, 0, scale, attn, 1048576L, 1024);
  softmax_rows<<<dim3(4096), dim3(256), 0, stream>>>(attn);
  // ot[b][n][c] = attn x v^T                           M=1024 N=512 K=1024, z=16
  gemm_bt<<<dim3(2, 4, 16), dim3(1024), SMEM, stream>>>(
      attn, vv2, 1048576L, 1024L, 1024, 16384, 1024,
      (const float*)nullptr, 0, 1.0f, ot, 524288L, 512);
  // po[c][bn] = wp x o + bp                            M=512 N=16384 K=512
  gemm_bt<<<dim3(64, 2, 1), dim3(1024), SMEM, stream>>>(
      w_bf + 3 * 262144, ot, 0L, 0L, 512, 512, 512,
      bp, 1, 1.0f, po, 0L, 16384);
  // out = x + po  (fp32)
  residual_add<<<dim3(4096), dim3(256), 0, stream>>>(x, po, (float*)d_out);
}

// Round 18
// 169.002 us; speedup vs baseline: 1.1581x; 1.0381x over previous
//
#include <hip/hip_runtime.h>
#include <hip/hip_bf16.h>

typedef __attribute__((ext_vector_type(8))) short bf16x8;
typedef __attribute__((ext_vector_type(4))) float f32x4;
typedef __attribute__((ext_vector_type(8))) unsigned short u16x8;
typedef __attribute__((ext_vector_type(4))) unsigned short u16x4;

static __device__ __forceinline__ unsigned short f2bf(float f) {
  __hip_bfloat16 h = __float2bfloat16(f);
  union { __hip_bfloat16 h; unsigned short u; } cv; cv.h = h; return cv.u;
}
static __device__ __forceinline__ float bf2f(unsigned short u) {
  union { unsigned int u; float f; } cv; cv.u = ((unsigned int)u) << 16; return cv.f;
}

static __device__ __forceinline__ void gload16(const unsigned short* g, unsigned short* l) {
  __builtin_amdgcn_global_load_lds((const __attribute__((address_space(1))) void*)g,
                                   (__attribute__((address_space(3))) void*)l, 16, 0, 0);
}

#define BK 64

// 128x128 tile, BK=64, 4 waves, single 32KB buffer (R15 verbatim — verified
// best for v / pv / po).  bf16 out.  XCD-swizzled block id (grids % 8 == 0).
__global__ __launch_bounds__(256, 4) void gemm_bt(
    const unsigned short* __restrict__ A, const unsigned short* __restrict__ Bm,
    long sA, long sB, int lda, int ldb, int K,
    const float* __restrict__ bias, int bias_mode, float post_scale,
    unsigned short* __restrict__ D, long sD, int ldd)
{
  __shared__ unsigned short lA[128 * BK];
  __shared__ unsigned short lB[128 * BK];
  const int gx = gridDim.x, gy = gridDim.y;
  const int nwg = gx * gy * gridDim.z;
  int orig = blockIdx.x + gx * (blockIdx.y + gy * blockIdx.z);
  int id = (orig & 7) * (nwg >> 3) + (orig >> 3);   // bijective: nwg % 8 == 0
  const int bxi = id % gx;
  int rem = id / gx;
  const int byi = rem % gy;
  const int bz = rem / gy;

  const int tid = threadIdx.x, lane = tid & 63, wid = tid >> 6;
  const int l15 = lane & 15, lhi = lane >> 4;
  const int wr = wid >> 1, wc = wid & 1;
  const long bm = (long)byi * 128, bn = (long)bxi * 128;
  const unsigned short* Ab = A + (size_t)bz * sA + (size_t)bm * lda;
  const unsigned short* Bb = Bm + (size_t)bz * sB + (size_t)bn * ldb;
  const int NT = K >> 6;

  f32x4 acc[4][4];
  #pragma unroll
  for (int i = 0; i < 4; ++i)
    #pragma unroll
    for (int j = 0; j < 4; ++j) acc[i][j] = (f32x4){0.f, 0.f, 0.f, 0.f};

  auto stage = [&](int k0) {
    #pragma unroll
    for (int j = 0; j < 4; ++j) {
      int bi = j * 256 + tid;
      int row = bi >> 3, sl = bi & 7;
      int kb = sl ^ (row & 7);
      gload16(Ab + (size_t)row * lda + k0 + kb * 8, &lA[(j * 256 + wid * 64) * 8]);
    }
    #pragma unroll
    for (int j = 0; j < 4; ++j) {
      int bi = j * 256 + tid;
      int row = bi >> 3, sl = bi & 7;
      int kb = sl ^ (row & 7);
      gload16(Bb + (size_t)row * ldb + k0 + kb * 8, &lB[(j * 256 + wid * 64) * 8]);
    }
  };

  for (int t = 0; t < NT; ++t) {
    stage(t * BK);
    __syncthreads();
    #pragma unroll
    for (int s = 0; s < 2; ++s) {
      bf16x8 af[4], bfr[4];
      #pragma unroll
      for (int mi = 0; mi < 4; ++mi) {
        int row = wr * 64 + mi * 16 + l15;
        int sl = (s * 4 + lhi) ^ (row & 7);
        af[mi] = *(const bf16x8*)&lA[row * BK + sl * 8];
      }
      #pragma unroll
      for (int ni = 0; ni < 4; ++ni) {
        int row = wc * 64 + ni * 16 + l15;
        int sl = (s * 4 + lhi) ^ (row & 7);
        bfr[ni] = *(const bf16x8*)&lB[row * BK + sl * 8];
      }
      #pragma unroll
      for (int mi = 0; mi < 4; ++mi)
        #pragma unroll
        for (int ni = 0; ni < 4; ++ni)
          acc[mi][ni] = __builtin_amdgcn_mfma_f32_16x16x32_bf16(af[mi], bfr[ni], acc[mi][ni], 0, 0, 0);
    }
    __syncthreads();
  }

  #pragma unroll
  for (int mi = 0; mi < 4; ++mi) {
    #pragma unroll
    for (int ni = 0; ni < 4; ++ni) {
      #pragma unroll
      for (int r = 0; r < 4; ++r) {
        long row = bm + wr * 64 + mi * 16 + lhi * 4 + r;
        long col = bn + wc * 64 + ni * 16 + l15;
        float v = acc[mi][ni][r];
        if (bias_mode == 1) v += bias[row];
        else if (bias_mode == 2) v += bias[col];
        v *= post_scale;
        D[(size_t)bz * sD + (size_t)row * ldd + col] = f2bf(v);
      }
    }
  }
}

// 128(M) x 256(N) tile, BK=64, 8 waves (512 thr), per-wave 64x64 — R14's
// verified wide kernel (absmax 0.03125).  Stages 196MB vs 256-268MB for the
// qk/attn shapes at 2 blocks/CU: the one tile change measured to beat 128x128
// on these two dispatches.  bf16 out.  XCD-swizzled (grids % 8 == 0).
__global__ __launch_bounds__(512, 4) void gemm_wide(
    const unsigned short* __restrict__ A, const unsigned short* __restrict__ Bm,
    long sA, long sB, int lda, int ldb, int K,
    const float* __restrict__ bias, int bias_mode, float post_scale,
    unsigned short* __restrict__ D, long sD, int ldd)
{
  __shared__ unsigned short lA[128 * BK];   // 16KB
  __shared__ unsigned short lB[256 * BK];   // 32KB
  const int gx = gridDim.x, gy = gridDim.y;
  const int nwg = gx * gy * gridDim.z;
  int orig = blockIdx.x + gx * (blockIdx.y + gy * blockIdx.z);
  int id = (orig & 7) * (nwg >> 3) + (orig >> 3);   // bijective: nwg % 8 == 0
  const int bxi = id % gx;
  int rem = id / gx;
  const int byi = rem % gy;
  const int bz = rem / gy;

  const int tid = threadIdx.x, lane = tid & 63, wid = tid >> 6;
  const int l15 = lane & 15, lhi = lane >> 4;
  const int wr = wid >> 2, wc = wid & 3;            // 2 M-halves x 4 N-quarters
  const long bm = (long)byi * 128, bn = (long)bxi * 256;
  const unsigned short* Ab = A + (size_t)bz * sA + (size_t)bm * lda;
  const unsigned short* Bb = Bm + (size_t)bz * sB + (size_t)bn * ldb;
  const int NT = K >> 6;

  f32x4 acc[4][4];
  #pragma unroll
  for (int i = 0; i < 4; ++i)
    #pragma unroll
    for (int j = 0; j < 4; ++j) acc[i][j] = (f32x4){0.f, 0.f, 0.f, 0.f};

  auto stage = [&](int k0) {
    #pragma unroll
    for (int j = 0; j < 2; ++j) {
      int bi = j * 512 + tid;
      int row = bi >> 3, sl = bi & 7;
      int kb = sl ^ (row & 7);
      gload16(Ab + (size_t)row * lda + k0 + kb * 8, &lA[(j * 512 + wid * 64) * 8]);
    }
    #pragma unroll
    for (int j = 0; j < 4; ++j) {
      int bi = j * 512 + tid;
      int row = bi >> 3, sl = bi & 7;
      int kb = sl ^ (row & 7);
      gload16(Bb + (size_t)row * ldb + k0 + kb * 8, &lB[(j * 512 + wid * 64) * 8]);
    }
  };

  for (int t = 0; t < NT; ++t) {
    stage(t * BK);
    __syncthreads();
    #pragma unroll
    for (int s = 0; s < 2; ++s) {
      bf16x8 af[4], bfr[4];
      #pragma unroll
      for (int mi = 0; mi < 4; ++mi) {
        int row = wr * 64 + mi * 16 + l15;
        int sl = (s * 4 + lhi) ^ (row & 7);
        af[mi] = *(const bf16x8*)&lA[row * BK + sl * 8];
      }
      #pragma unroll
      for (int ni = 0; ni < 4; ++ni) {
        int row = wc * 64 + ni * 16 + l15;
        int sl = (s * 4 + lhi) ^ (row & 7);
        bfr[ni] = *(const bf16x8*)&lB[row * BK + sl * 8];
      }
      #pragma unroll
      for (int mi = 0; mi < 4; ++mi)
        #pragma unroll
        for (int ni = 0; ni < 4; ++ni)
          acc[mi][ni] = __builtin_amdgcn_mfma_f32_16x16x32_bf16(af[mi], bfr[ni], acc[mi][ni], 0, 0, 0);
    }
    __syncthreads();
  }

  #pragma unroll
  for (int mi = 0; mi < 4; ++mi) {
    #pragma unroll
    for (int ni = 0; ni < 4; ++ni) {
      #pragma unroll
      for (int r = 0; r < 4; ++r) {
        long row = bm + wr * 64 + mi * 16 + lhi * 4 + r;
        long col = bn + wc * 64 + ni * 16 + l15;
        float v = acc[mi][ni][r];
        if (bias_mode == 1) v += bias[row];
        else if (bias_mode == 2) v += bias[col];
        v *= post_scale;
        D[(size_t)bz * sD + (size_t)row * ldd + col] = f2bf(v);
      }
    }
  }
}

// Single-pass GroupNorm; writes h transposed: ht[b][n][c] bf16.
__global__ __launch_bounds__(256) void groupnorm_to_ht(
    const float* __restrict__ x, const float* __restrict__ gamma,
    const float* __restrict__ beta, unsigned short* __restrict__ ht)
{
  const int b = blockIdx.x >> 5;
  const int g = blockIdx.x & 31;
  const int tid = threadIdx.x, lane = tid & 63, wid = tid >> 6;
  const float4* xg4 = (const float4*)(x + ((size_t)b * 512 + g * 16) * 1024);
  float4 v[16];
  float s = 0.f, ss = 0.f;
  #pragma unroll
  for (int j = 0; j < 16; ++j) {
    v[j] = xg4[j * 256 + tid];
    s += v[j].x + v[j].y + v[j].z + v[j].w;
    ss += v[j].x * v[j].x + v[j].y * v[j].y + v[j].z * v[j].z + v[j].w * v[j].w;
  }
  #pragma unroll
  for (int o = 32; o; o >>= 1) { s += __shfl_xor(s, o); ss += __shfl_xor(ss, o); }
  __shared__ float red[8];
  if (lane == 0) { red[wid] = s; red[4 + wid] = ss; }
  __syncthreads();
  s = red[0] + red[1] + red[2] + red[3];
  ss = red[4] + red[5] + red[6] + red[7];
  const float mu = s * (1.f / 16384.f);
  const float var = ss * (1.f / 16384.f) - mu * mu;
  const float rsig = rsqrtf(var + 1e-5f);
  __shared__ unsigned short tile[16][1024];
  #pragma unroll
  for (int j = 0; j < 16; ++j) {
    int e = (j * 256 + tid) * 4;
    int ci = e >> 10, n = e & 1023;
    float ga = gamma[g * 16 + ci] * rsig, be = beta[g * 16 + ci];
    u16x4 o = { f2bf((v[j].x - mu) * ga + be), f2bf((v[j].y - mu) * ga + be),
                f2bf((v[j].z - mu) * ga + be), f2bf((v[j].w - mu) * ga + be) };
    *(u16x4*)&tile[ci][n] = o;
  }
  __syncthreads();
  unsigned short* hb = ht + (size_t)b * 1024 * 512 + g * 16;
  for (int rep = 0; rep < 4; ++rep) {
    int n = rep * 256 + tid;
    u16x8 lo, hi;
    #pragma unroll
    for (int ci = 0; ci < 8; ++ci) lo[ci] = tile[ci][n];
    #pragma unroll
    for (int ci = 0; ci < 8; ++ci) hi[ci] = tile[8 + ci][n];
    *(u16x8*)&hb[(size_t)n * 512] = lo;
    *(u16x8*)&hb[(size_t)n * 512 + 8] = hi;
  }
}

// Row softmax in place over 1024 bf16 logits; one wave per row.
__global__ __launch_bounds__(256) void softmax_rows(unsigned short* __restrict__ attn)
{
  int row = blockIdx.x * 4 + (threadIdx.x >> 6);
  int lane = threadIdx.x & 63;
  unsigned short* p = attn + (size_t)row * 1024;
  u16x8 c0 = *(const u16x8*)&p[lane * 8];
  u16x8 c1 = *(const u16x8*)&p[512 + lane * 8];
  float f[16];
  #pragma unroll
  for (int j = 0; j < 8; ++j) { f[j] = bf2f(c0[j]); f[8 + j] = bf2f(c1[j]); }
  float m = f[0];
  #pragma unroll
  for (int j = 1; j < 16; ++j) m = fmaxf(m, f[j]);
  #pragma unroll
  for (int o = 32; o; o >>= 1) m = fmaxf(m, __shfl_xor(m, o));
  float sum = 0.f;
  #pragma unroll
  for (int j = 0; j < 16; ++j) { f[j] = __expf(f[j] - m); sum += f[j]; }
  #pragma unroll
  for (int o = 32; o; o >>= 1) sum += __shfl_xor(sum, o);
  float inv = 1.0f / sum;
  #pragma unroll
  for (int j = 0; j < 8; ++j) { c0[j] = f2bf(f[j] * inv); c1[j] = f2bf(f[8 + j] * inv); }
  *(u16x8*)&p[lane * 8] = c0;
  *(u16x8*)&p[512 + lane * 8] = c1;
}

// out[b][c][n] = x[b][c][n] + po[c][b*1024+n]   (fp32 residual, vectorized)
__global__ __launch_bounds__(256) void residual_add(
    const float* __restrict__ x, const unsigned short* __restrict__ po,
    float* __restrict__ out)
{
  int t = blockIdx.x * 256 + threadIdx.x;
  int idx = t * 8;
  int b = idx >> 19, c = (idx >> 10) & 511, n = idx & 1023;
  u16x8 g = *(const u16x8*)&po[(size_t)c * 16384 + b * 1024 + n];
  float4 x0 = *(const float4*)&x[idx];
  float4 x1 = *(const float4*)&x[idx + 4];
  float4 o0 = { x0.x + bf2f(g[0]), x0.y + bf2f(g[1]), x0.z + bf2f(g[2]), x0.w + bf2f(g[3]) };
  float4 o1 = { x1.x + bf2f(g[4]), x1.y + bf2f(g[5]), x1.z + bf2f(g[6]), x1.w + bf2f(g[7]) };
  *(float4*)&out[idx] = o0;
  *(float4*)&out[idx + 4] = o1;
}

__global__ __launch_bounds__(256) void convert_weights(
    const float* __restrict__ wq, const float* __restrict__ wk,
    const float* __restrict__ wv, const float* __restrict__ wp,
    const float* __restrict__ bq, const float* __restrict__ bk,
    unsigned short* __restrict__ out, float* __restrict__ bqk)
{
  if (blockIdx.x == 1024) {          // build concatenated q||k bias
    int i = threadIdx.x * 4;
    if (i < 512) *(float4*)&bqk[i] = *(const float4*)&bq[i];
    else         *(float4*)&bqk[i] = *(const float4*)&bk[i - 512];
    return;
  }
  int t = blockIdx.x * 256 + threadIdx.x;
  int m = t >> 16;
  int off = (t & 65535) * 4;
  const float* src = m == 0 ? wq : m == 1 ? wk : m == 2 ? wv : wp;
  float4 v = *(const float4*)&src[off];
  u16x4 o = { f2bf(v.x), f2bf(v.y), f2bf(v.z), f2bf(v.w) };
  *(u16x4*)&out[(size_t)m * 262144 + off] = o;
}

extern "C" void kernel_launch(void* const* d_in, const int* in_sizes, int n_in,
                              void* d_out, int out_size, void* d_ws, size_t ws_size,
                              hipStream_t stream)
{
  const float* x     = (const float*)d_in[0];
  const float* gamma = (const float*)d_in[1];
  const float* beta  = (const float*)d_in[2];
  const float* wq    = (const float*)d_in[3];
  const float* bq    = (const float*)d_in[4];
  const float* wk    = (const float*)d_in[5];
  const float* bk    = (const float*)d_in[6];
  const float* wv    = (const float*)d_in[7];
  const float* bv    = (const float*)d_in[8];
  const float* wp    = (const float*)d_in[9];
  const float* bp    = (const float*)d_in[10];

  unsigned short* ws   = (unsigned short*)d_ws;
  unsigned short* w_bf = ws;                               // [4][512][512]
  unsigned short* ht   = w_bf + 1048576;                   // [B*N][C]
  unsigned short* qk   = ht + 8388608;                     // [B*N][2C]  (q||k)
  unsigned short* vv2  = qk + 16777216;                    // [C][B*N]
  unsigned short* attn = vv2 + 8388608;                    // [B][N][N]; reused as po [C][B*N]
  unsigned short* ot   = attn + 16777216;                  // [B*N][C]
  float*          bqk  = (float*)(ot + 8388608);           // [1024]
  unsigned short* po   = attn;                             // reuse after PV

  const float scale = 0.044194173824159216f;               // 512^-0.5

  convert_weights<<<dim3(1025), dim3(256), 0, stream>>>(wq, wk, wv, wp, bq, bk, w_bf, bqk);
  groupnorm_to_ht<<<dim3(512), dim3(256), 0, stream>>>(x, gamma, beta, ht);

  // qk[bn][0..1024) = ht x [wq;wk]^T + (bq||bk)       M=16384 N=1024 K=512  (wide)
  gemm_wide<<<dim3(4, 128, 1), dim3(512), 0, stream>>>(
      ht, w_bf, 0L, 0L, 512, 512, 512,
      bqk, 2, 1.0f, qk, 0L, 1024);
  // vv2[c][bn] = wv x h + bv                           M=512 N=16384 K=512
  gemm_bt<<<dim3(128, 4, 1), dim3(256), 0, stream>>>(
      w_bf + 2 * 262144, ht, 0L, 0L, 512, 512, 512,
      bv, 1, 1.0f, vv2, 0L, 16384);
  // attn[b][n][m] = scale * (q_n . k_m)                M=1024 N=1024 K=512, z=16  (wide)
  gemm_wide<<<dim3(4, 8, 16), dim3(512), 0, stream>>>(
      qk, qk + 512, 1048576L, 1048576L, 1024, 1024, 512,
      (const float*)nullptr, 0, scale, attn, 1048576L, 1024);
  softmax_rows<<<dim3(4096), dim3(256), 0, stream>>>(attn);
  // ot[b][n][c] = attn x v^T                           M=1024 N=512 K=1024, z=16
  gemm_bt<<<dim3(4, 8, 16), dim3(256), 0, stream>>>(
      attn, vv2, 1048576L, 1024L, 1024, 16384, 1024,
      (const float*)nullptr, 0, 1.0f, ot, 524288L, 512);
  // po[c][bn] = wp x o + bp                            M=512 N=16384 K=512
  gemm_bt<<<dim3(128, 4, 1), dim3(256), 0, stream>>>(
      w_bf + 3 * 262144, ot, 0L, 0L, 512, 512, 512,
      bp, 1, 1.0f, po, 0L, 16384);
  // out = x + po  (fp32)
  residual_add<<<dim3(4096), dim3(256), 0, stream>>>(x, po, (float*)d_out);
}